// Round 1
// baseline (1589.255 us; speedup 1.0000x reference)
//
#include <hip/hip_runtime.h>
#include <hip/hip_fp16.h>
#include <math.h>

#define NROWS 8192
#define DIM 512

typedef _Float16 half8 __attribute__((ext_vector_type(8)));
typedef float f32x4 __attribute__((ext_vector_type(4)));

__device__ __forceinline__ f32x4 mfma16(half8 a, half8 b, f32x4 c) {
  return __builtin_amdgcn_mfma_f32_16x16x32_f16(a, b, c, 0, 0, 0);
}

// ---------------------------------------------------------------------------
// Generic 8192x512 = (8192x512)@(512x512) + bias GEMM, f16 MFMA, fp32 accum.
// mode 0: out f16 row-major
// mode 1: out f16 TRANSPOSED (Vt[n][m], for retention B-fragments)
// mode 2: gelu(v), out f16 row-major
// mode 3: out f32 row-major
// ---------------------------------------------------------------------------
template<typename AT>
__global__ __launch_bounds__(256) void gemm512(
    const AT* __restrict__ A, const float* __restrict__ B,
    const float* __restrict__ bias, void* __restrict__ out, int mode)
{
  __shared__ _Float16 As[64][40];   // 64 rows x 32 k, stride 40 (80B, 16B-aligned)
  __shared__ _Float16 Bs[64][40];   // 64 cols x 32 k (B transposed)

  const int m0 = blockIdx.x * 64;
  const int n0 = blockIdx.y * 64;
  const int tid  = threadIdx.x;
  const int lane = tid & 63;
  const int w    = tid >> 6;        // wave 0..3
  const int wm   = w & 1;           // wave row-block (32)
  const int wn   = w >> 1;          // wave col-block (32)
  const int lr   = lane & 15;
  const int lk   = (lane >> 4) * 8;

  f32x4 acc[2][2] = {};

  const int sr   = tid >> 2;        // A-staging row 0..63
  const int skb  = (tid & 3) * 8;   // A-staging k base
  const int scn  = tid & 63;        // B-staging col
  const int skb2 = (tid >> 6) * 8;  // B-staging k base

  for (int k0 = 0; k0 < 512; k0 += 32) {
    { // stage A (convert to f16 if fp32)
      half8 h;
      const AT* src = A + (size_t)(m0 + sr) * 512 + k0 + skb;
      if constexpr (sizeof(AT) == 4) {
        float4 f0 = *(const float4*)(src);
        float4 f1 = *(const float4*)(src + 4);
        h[0] = (_Float16)f0.x; h[1] = (_Float16)f0.y;
        h[2] = (_Float16)f0.z; h[3] = (_Float16)f0.w;
        h[4] = (_Float16)f1.x; h[5] = (_Float16)f1.y;
        h[6] = (_Float16)f1.z; h[7] = (_Float16)f1.w;
      } else {
        h = *(const half8*)(src);
      }
      *(half8*)&As[sr][skb] = h;
    }
    { // stage B transposed: thread reads 8 consecutive k of one column (coalesced over n)
      const float* src = B + (size_t)(k0 + skb2) * 512 + n0 + scn;
      half8 h;
      #pragma unroll
      for (int j = 0; j < 8; ++j) h[j] = (_Float16)src[(size_t)j * 512];
      *(half8*)&Bs[scn][skb2] = h;
    }
    __syncthreads();
    half8 af0 = *(const half8*)&As[wm*32      + lr][lk];
    half8 af1 = *(const half8*)&As[wm*32 + 16 + lr][lk];
    half8 bf0 = *(const half8*)&Bs[wn*32      + lr][lk];
    half8 bf1 = *(const half8*)&Bs[wn*32 + 16 + lr][lk];
    acc[0][0] = mfma16(af0, bf0, acc[0][0]);
    acc[0][1] = mfma16(af0, bf1, acc[0][1]);
    acc[1][0] = mfma16(af1, bf0, acc[1][0]);
    acc[1][1] = mfma16(af1, bf1, acc[1][1]);
    __syncthreads();
  }

  // epilogue: D layout col = lane&15, row = (lane>>4)*4 + i  [HW-verified]
  #pragma unroll
  for (int mi = 0; mi < 2; ++mi) {
    #pragma unroll
    for (int ni = 0; ni < 2; ++ni) {
      const int gc = n0 + wn*32 + ni*16 + lr;
      const float bv = bias[gc];
      #pragma unroll
      for (int i = 0; i < 4; ++i) {
        const int gr = m0 + wm*32 + mi*16 + (lane >> 4)*4 + i;
        float v = acc[mi][ni][i] + bv;
        if (mode == 2) v = 0.5f * v * (1.0f + erff(v * 0.70710678118f));
        if (mode == 1) {
          ((_Float16*)out)[(size_t)gc * NROWS + gr] = (_Float16)v;
        } else if (mode == 3) {
          ((float*)out)[(size_t)gr * 512 + gc] = v;
        } else {
          ((_Float16*)out)[(size_t)gr * 512 + gc] = (_Float16)v;
        }
      }
    }
  }
}

// ---------------------------------------------------------------------------
// Fused retention: Xret = (D ∘ (Q @ K^T)) @ V, never materializing S.
// Block: 32 rows of Q/Xret, 512 threads (8 waves). J-tile = 64.
// Wave w: S-fragment (sm = w>>2, sn = w&3); PV rows sm*16, cols (w&3)*128.
// Q held in registers (16 a-frags). K/Vt b-frags loaded straight from global.
// P = D*S round-trips through a 4.6KB LDS tile.
// ---------------------------------------------------------------------------
__global__ __launch_bounds__(512, 2) void retention(
    const _Float16* __restrict__ Qh, const _Float16* __restrict__ Kh,
    const _Float16* __restrict__ Vt, const float* __restrict__ D,
    _Float16* __restrict__ Xret)
{
  __shared__ _Float16 Ps[32][72];   // 32 rows x 64 j, stride 72 (144B, 16B-aligned)

  const int I0   = blockIdx.x * 32;
  const int tid  = threadIdx.x;
  const int lane = tid & 63;
  const int w    = tid >> 6;        // 0..7
  const int sm   = w >> 2;          // 0..1  (16-row tile)
  const int sn   = w & 3;           // 0..3  (16-col tile of S / j)
  const int lr   = lane & 15;
  const int lkb  = lane >> 4;       // 0..3
  const int lk   = lkb * 8;

  // preload this wave's Q a-fragments (rows I0 + sm*16, full K=512)
  half8 q[16];
  {
    const _Float16* qrow = Qh + (size_t)(I0 + sm*16 + lr) * 512 + lk;
    #pragma unroll
    for (int ks = 0; ks < 16; ++ks) q[ks] = *(const half8*)(qrow + ks*32);
  }

  f32x4 acc[8] = {};                // 8 n-tiles of 16 cols = 128 cols per wave
  const int nq = (w & 3) * 128;
  const int prow = I0 + sm*16 + lkb*4;   // base row for D reads / S rows

  for (int J = 0; J < NROWS; J += 64) {
    // ---- S-fragment: Q(16x512) @ K^T(512x16), two interleaved partials
    f32x4 s0 = {}, s1 = {};
    const _Float16* krow = Kh + (size_t)(J + sn*16 + lr) * 512 + lk;
    #pragma unroll
    for (int ks = 0; ks < 16; ks += 2) {
      s0 = mfma16(q[ks],     *(const half8*)(krow + ks*32),       s0);
      s1 = mfma16(q[ks + 1], *(const half8*)(krow + (ks+1)*32),   s1);
    }
    // ---- P = D * S -> f16 -> LDS
    #pragma unroll
    for (int i = 0; i < 4; ++i) {
      float sv = s0[i] + s1[i];
      float d  = D[(size_t)(prow + i) * NROWS + J + sn*16 + lr];
      Ps[sm*16 + lkb*4 + i][sn*16 + lr] = (_Float16)(sv * d);
    }
    __syncthreads();
    // ---- PV: acc += P(16x64) @ V(64x128-slice)
    half8 pa0 = *(const half8*)&Ps[sm*16 + lr][lk];        // j 0..31 window
    half8 pa1 = *(const half8*)&Ps[sm*16 + lr][32 + lk];   // j 32..63 window
    #pragma unroll
    for (int nt = 0; nt < 8; ++nt) {
      const _Float16* vrow = Vt + (size_t)(nq + nt*16 + lr) * NROWS + J + lk;
      acc[nt] = mfma16(pa0, *(const half8*)(vrow),      acc[nt]);
      acc[nt] = mfma16(pa1, *(const half8*)(vrow + 32), acc[nt]);
    }
    __syncthreads();
  }

  #pragma unroll
  for (int nt = 0; nt < 8; ++nt) {
    #pragma unroll
    for (int i = 0; i < 4; ++i) {
      Xret[(size_t)(I0 + sm*16 + lkb*4 + i) * 512 + nq + nt*16 + lr] =
          (_Float16)acc[nt][i];
    }
  }
}

// ---------------------------------------------------------------------------
// GroupNorm: 8192 rows, 512 channels, 16 groups of 32. One block per row.
// ---------------------------------------------------------------------------
__global__ __launch_bounds__(256) void gnorm(
    const float* __restrict__ in, const float* __restrict__ gamma,
    const float* __restrict__ beta, float* __restrict__ out)
{
  const int row = blockIdx.x;
  const int t = threadIdx.x;
  const int c = t * 2;                       // 2 channels/thread, group = t>>4
  float2 v = *(const float2*)(in + (size_t)row * 512 + c);
  float s  = v.x + v.y;
  float s2 = v.x*v.x + v.y*v.y;
  #pragma unroll
  for (int m = 1; m <= 8; m <<= 1) {         // reduce over 16 threads (same group)
    s  += __shfl_xor(s, m, 64);
    s2 += __shfl_xor(s2, m, 64);
  }
  float mu  = s * (1.0f / 32.0f);
  float var = s2 * (1.0f / 32.0f) - mu * mu;
  float rs  = rsqrtf(var + 1e-5f);
  float2 o;
  o.x = (v.x - mu) * rs * gamma[c]     + beta[c];
  o.y = (v.y - mu) * rs * gamma[c + 1] + beta[c + 1];
  *(float2*)(out + (size_t)row * 512 + c) = o;
}

// ---------------------------------------------------------------------------
extern "C" void kernel_launch(void* const* d_in, const int* in_sizes, int n_in,
                              void* d_out, int out_size, void* d_ws, size_t ws_size,
                              hipStream_t stream)
{
  const float* x  = (const float*)d_in[0];
  const float* D  = (const float*)d_in[1];
  const float* Wq = (const float*)d_in[2];
  const float* bq = (const float*)d_in[3];
  const float* Wk = (const float*)d_in[4];
  const float* bk = (const float*)d_in[5];
  const float* Wv = (const float*)d_in[6];
  const float* bv = (const float*)d_in[7];
  const float* Wf = (const float*)d_in[8];
  const float* bf = (const float*)d_in[9];
  const float* Wp = (const float*)d_in[10];
  const float* bp = (const float*)d_in[11];
  const float* gamma = (const float*)d_in[12];
  const float* beta  = (const float*)d_in[13];

  char* ws = (char*)d_ws;
  const size_t MB = 1024 * 1024;
  _Float16* Qh  = (_Float16*)(ws);               //  8 MB: Q   f16 [8192][512]
  _Float16* Kh  = (_Float16*)(ws + 8  * MB);     //  8 MB: K   f16 [8192][512]
  _Float16* Vt  = (_Float16*)(ws + 16 * MB);     //  8 MB: V^T f16 [512][8192]
  _Float16* Xr  = (_Float16*)(ws + 24 * MB);     //  8 MB: x_ret f16 [8192][512]
  _Float16* Hh  = (_Float16*)(ws + 32 * MB);     //  8 MB: h   f16 [8192][512]
  float*    Pre = (float*)   (ws + 40 * MB);     // 16 MB: pre-GN f32 [8192][512]

  dim3 ggrid(128, 8), gblk(256);
  hipLaunchKernelGGL((gemm512<float>),    ggrid, gblk, 0, stream, x,  Wq, bq, (void*)Qh,  0);
  hipLaunchKernelGGL((gemm512<float>),    ggrid, gblk, 0, stream, x,  Wk, bk, (void*)Kh,  0);
  hipLaunchKernelGGL((gemm512<float>),    ggrid, gblk, 0, stream, x,  Wv, bv, (void*)Vt,  1);
  hipLaunchKernelGGL(retention, dim3(256), dim3(512), 0, stream, Qh, Kh, Vt, D, Xr);
  hipLaunchKernelGGL((gemm512<_Float16>), ggrid, gblk, 0, stream, Xr, Wf, bf, (void*)Hh,  2);
  hipLaunchKernelGGL((gemm512<_Float16>), ggrid, gblk, 0, stream, Hh, Wp, bp, (void*)Pre, 3);
  hipLaunchKernelGGL(gnorm, dim3(NROWS), dim3(256), 0, stream, Pre, gamma, beta, (float*)d_out);
}

// Round 2
// 740.283 us; speedup vs baseline: 2.1468x; 2.1468x over previous
//
#include <hip/hip_runtime.h>
#include <hip/hip_fp16.h>
#include <math.h>

#define NROWS 8192
#define DIM 512

typedef _Float16 half8 __attribute__((ext_vector_type(8)));
typedef _Float16 half4 __attribute__((ext_vector_type(4)));
typedef float f32x4 __attribute__((ext_vector_type(4)));

__device__ __forceinline__ f32x4 mfma16(half8 a, half8 b, f32x4 c) {
  return __builtin_amdgcn_mfma_f32_16x16x32_f16(a, b, c, 0, 0, 0);
}

// ---------------------------------------------------------------------------
// prep: x (f32) -> xh (f16); 5 weight matrices -> transposed f16 WT[wi][n][k].
// blocks 0..255: x conversion. blocks 256..895: W transposes (128 blocks/W).
// ---------------------------------------------------------------------------
__global__ __launch_bounds__(256) void prep(
    const float* __restrict__ x,
    const float* __restrict__ Wq, const float* __restrict__ Wk,
    const float* __restrict__ Wv, const float* __restrict__ Wf,
    const float* __restrict__ Wp,
    _Float16* __restrict__ xh, _Float16* __restrict__ WT)
{
  const int bid = blockIdx.x, tid = threadIdx.x;
  if (bid < 256) {
    const int base = bid * 16384 + tid * 4;
    #pragma unroll
    for (int r = 0; r < 16; ++r) {
      float4 v = *(const float4*)(x + base + r * 1024);
      half4 h;
      h[0] = (_Float16)v.x; h[1] = (_Float16)v.y;
      h[2] = (_Float16)v.z; h[3] = (_Float16)v.w;
      *(half4*)(xh + base + r * 1024) = h;
    }
  } else {
    const int wb = bid - 256;           // 0..639
    const int wi = wb >> 7;             // which W
    const int th = (wb & 127) * 256 + tid;  // 0..32767
    const int n = th >> 6, kc = th & 63;
    const float* W = (wi == 0) ? Wq : (wi == 1) ? Wk : (wi == 2) ? Wv
                   : (wi == 3) ? Wf : Wp;
    half8 h;
    #pragma unroll
    for (int j = 0; j < 8; ++j) h[j] = (_Float16)W[(size_t)(kc * 8 + j) * 512 + n];
    *(half8*)(WT + (size_t)wi * 262144 + (size_t)n * 512 + kc * 8) = h;
  }
}

// ---------------------------------------------------------------------------
// Fused QKV: Q = xh@Wq+bq, K = xh@Wk+bk, V = xh@Wv+bv.
// M-tile 32 (grid 256), 8 waves. A-tile staged once in LDS (padded rows,
// 1040B = 65x16 stride -> ~2-way conflicts); B-frags straight from L2-resident
// WT. No barriers in the k-loop. Q,K written row-major f16; V written
// TRANSPOSED (Vt[n][m]) as 8B packed stores.
// ---------------------------------------------------------------------------
__global__ __launch_bounds__(512, 2) void qkv(
    const _Float16* __restrict__ xh, const _Float16* __restrict__ WT,
    const float* __restrict__ bq, const float* __restrict__ bk,
    const float* __restrict__ bv,
    _Float16* __restrict__ Qh, _Float16* __restrict__ Kh,
    _Float16* __restrict__ Vt)
{
  __shared__ _Float16 As[32][520];
  const int M0 = blockIdx.x * 32;
  const int tid = threadIdx.x;
  const int lane = tid & 63;
  const int w = tid >> 6;       // 0..7
  const int lr = lane & 15;
  const int lkb = lane >> 4;    // 0..3

  // stage A-tile (32x512 f16 = 32KB), 4 x 16B chunks/thread
  #pragma unroll
  for (int j = 0; j < 4; ++j) {
    int c = tid + 512 * j;
    int r = c >> 6, c16 = c & 63;
    half8 h = *(const half8*)(xh + (size_t)(M0 + r) * 512 + c16 * 8);
    *(half8*)&As[r][c16 * 8] = h;
  }
  __syncthreads();

  const _Float16* WqT = WT;
  const _Float16* WkT = WT + 262144;
  const _Float16* WvT = WT + 524288;

  f32x4 aq[2][4] = {}, ak[2][4] = {}, av[2][4] = {};

  for (int ks = 0; ks < 16; ++ks) {
    half8 a0 = *(const half8*)&As[lr][ks * 32 + lkb * 8];
    half8 a1 = *(const half8*)&As[16 + lr][ks * 32 + lkb * 8];
    #pragma unroll
    for (int nt = 0; nt < 4; ++nt) {
      const size_t boff = (size_t)(w * 64 + nt * 16 + lr) * 512 + ks * 32 + lkb * 8;
      half8 bqf = *(const half8*)(WqT + boff);
      half8 bkf = *(const half8*)(WkT + boff);
      half8 bvf = *(const half8*)(WvT + boff);
      aq[0][nt] = mfma16(a0, bqf, aq[0][nt]);
      aq[1][nt] = mfma16(a1, bqf, aq[1][nt]);
      ak[0][nt] = mfma16(a0, bkf, ak[0][nt]);
      ak[1][nt] = mfma16(a1, bkf, ak[1][nt]);
      av[0][nt] = mfma16(a0, bvf, av[0][nt]);
      av[1][nt] = mfma16(a1, bvf, av[1][nt]);
    }
  }

  #pragma unroll
  for (int mt = 0; mt < 2; ++mt) {
    #pragma unroll
    for (int nt = 0; nt < 4; ++nt) {
      const int col = w * 64 + nt * 16 + lr;
      const float vbq = bq[col], vbk = bk[col], vbv = bv[col];
      const int row0 = M0 + mt * 16 + lkb * 4;
      #pragma unroll
      for (int i = 0; i < 4; ++i) {
        Qh[(size_t)(row0 + i) * 512 + col] = (_Float16)(aq[mt][nt][i] + vbq);
        Kh[(size_t)(row0 + i) * 512 + col] = (_Float16)(ak[mt][nt][i] + vbk);
      }
      half4 pk;
      #pragma unroll
      for (int i = 0; i < 4; ++i) pk[i] = (_Float16)(av[mt][nt][i] + vbv);
      *(half4*)(Vt + (size_t)col * NROWS + row0) = pk;   // transposed, 8B store
    }
  }
}

// ---------------------------------------------------------------------------
// Retention v2: Xp[Jc] += (D ∘ (Q K^T)) V over J-chunk. I-tile 64, J-tile 32,
// double-buffered LDS K/V tiles (padded odd*16B strides), Q in registers,
// issue-early/write-late staging. Jc = bid&1 -> XCD parity locality.
// ---------------------------------------------------------------------------
__global__ __launch_bounds__(512, 2) void retention(
    const _Float16* __restrict__ Qh, const _Float16* __restrict__ Kh,
    const _Float16* __restrict__ Vt, const float* __restrict__ D,
    float* __restrict__ Xp0, float* __restrict__ Xp1)
{
  __shared__ _Float16 Ks[2][32][520];   // 65KB: K rows (j) x k, stride 1040B
  __shared__ _Float16 Vs[2][512][40];   // 80KB: V^T rows (n) x j, stride 80B
  __shared__ _Float16 Ps[64][40];       //  5KB: P rows (i) x j, stride 80B

  const int bid = blockIdx.x;
  const int Jc = bid & 1;
  const int I0 = (bid >> 1) * 64;
  const int Jbase = Jc * 4096;
  float* __restrict__ Xp = Jc ? Xp1 : Xp0;

  const int tid = threadIdx.x;
  const int lane = tid & 63;
  const int w = tid >> 6;     // 0..7
  const int wr = w >> 1;      // 0..3 (16-row group)
  const int wc = w & 1;       // 0..1
  const int lr = lane & 15;
  const int lkb = lane >> 4;  // 0..3

  // Q preload: 16 a-frags covering K=512 for rows I0 + wr*16 + (0..15)
  half8 q[16];
  {
    const _Float16* qrow = Qh + (size_t)(I0 + wr * 16 + lr) * 512 + lkb * 8;
    #pragma unroll
    for (int ks = 0; ks < 16; ++ks) q[ks] = *(const half8*)(qrow + ks * 32);
  }

  // staging assignments
  int kr[4], kc16[4], vn[4], vjc[4];
  #pragma unroll
  for (int j = 0; j < 4; ++j) {
    int c = tid + 512 * j;
    kr[j] = c >> 6;  kc16[j] = c & 63;   // K: row 0..31, 16B chunk 0..63
    vn[j] = c >> 2;  vjc[j]  = c & 3;    // V: row n 0..511, 16B chunk 0..3
  }

  // prologue: stage tile 0 into buffer 0
  {
    #pragma unroll
    for (int j = 0; j < 4; ++j) {
      half8 kd = *(const half8*)(Kh + (size_t)(Jbase + kr[j]) * 512 + kc16[j] * 8);
      half8 vd = *(const half8*)(Vt + (size_t)vn[j] * NROWS + Jbase + vjc[j] * 8);
      *(half8*)&Ks[0][kr[j]][kc16[j] * 8] = kd;
      *(half8*)&Vs[0][vn[j]][vjc[j] * 8] = vd;
    }
  }
  __syncthreads();

  f32x4 acc[16] = {};

  for (int t = 0; t < 128; ++t) {
    const int cur = t & 1;
    const int Jb = Jbase + t * 32;
    const bool more = (t + 1 < 128);

    // issue next tile's global loads early (write-late into buf cur^1)
    half8 kd[4], vd[4];
    if (more) {
      const int Jn = Jb + 32;
      #pragma unroll
      for (int j = 0; j < 4; ++j) {
        kd[j] = *(const half8*)(Kh + (size_t)(Jn + kr[j]) * 512 + kc16[j] * 8);
        vd[j] = *(const half8*)(Vt + (size_t)vn[j] * NROWS + Jn + vjc[j] * 8);
      }
    }

    // D loads (HBM stream) issued before the MFMA chain
    float dv[4];
    #pragma unroll
    for (int i = 0; i < 4; ++i)
      dv[i] = D[(size_t)(I0 + wr * 16 + lkb * 4 + i) * NROWS + Jb + wc * 16 + lr];

    // ---- S = Q K^T (16 rows x 16 cols per wave), 4 partial chains
    f32x4 s[4] = {};
    #pragma unroll
    for (int ks = 0; ks < 16; ++ks) {
      half8 kb = *(const half8*)&Ks[cur][wc * 16 + lr][ks * 32 + lkb * 8];
      s[ks & 3] = mfma16(q[ks], kb, s[ks & 3]);
    }
    #pragma unroll
    for (int i = 0; i < 4; ++i) {
      float sv = (s[0][i] + s[1][i]) + (s[2][i] + s[3][i]);
      Ps[wr * 16 + lkb * 4 + i][wc * 16 + lr] = (_Float16)(sv * dv[i]);
    }
    __syncthreads();

    // ---- PV: acc += P(16x32) @ V(32x256-slice); 16 independent chains
    half8 pa = *(const half8*)&Ps[wr * 16 + lr][lkb * 8];
    #pragma unroll
    for (int nt = 0; nt < 16; ++nt) {
      half8 vb = *(const half8*)&Vs[cur][wc * 256 + nt * 16 + lr][lkb * 8];
      acc[nt] = mfma16(pa, vb, acc[nt]);
    }

    // write-late: next tile into the other buffer
    if (more) {
      #pragma unroll
      for (int j = 0; j < 4; ++j) {
        *(half8*)&Ks[cur ^ 1][kr[j]][kc16[j] * 8] = kd[j];
        *(half8*)&Vs[cur ^ 1][vn[j]][vjc[j] * 8] = vd[j];
      }
    }
    __syncthreads();
  }

  #pragma unroll
  for (int nt = 0; nt < 16; ++nt) {
    #pragma unroll
    for (int i = 0; i < 4; ++i)
      Xp[(size_t)(I0 + wr * 16 + lkb * 4 + i) * 512 + wc * 256 + nt * 16 + lr] =
          acc[nt][i];
  }
}

// ---------------------------------------------------------------------------
// mlp1: h = gelu((Xp0+Xp1) @ Wf + bf) -> f16. Same skeleton as qkv, 1 matrix.
// ---------------------------------------------------------------------------
__global__ __launch_bounds__(512, 2) void mlp1(
    const float* __restrict__ Xp0, const float* __restrict__ Xp1,
    const _Float16* __restrict__ WfT, const float* __restrict__ bf,
    _Float16* __restrict__ Hh)
{
  __shared__ _Float16 As[32][520];
  const int M0 = blockIdx.x * 32;
  const int tid = threadIdx.x;
  const int lane = tid & 63;
  const int w = tid >> 6;
  const int lr = lane & 15;
  const int lkb = lane >> 4;

  #pragma unroll
  for (int j = 0; j < 4; ++j) {
    int c = tid + 512 * j;
    int r = c >> 6, c16 = c & 63;
    const size_t off = (size_t)(M0 + r) * 512 + c16 * 8;
    float4 a0 = *(const float4*)(Xp0 + off);
    float4 a1 = *(const float4*)(Xp0 + off + 4);
    float4 b0 = *(const float4*)(Xp1 + off);
    float4 b1 = *(const float4*)(Xp1 + off + 4);
    half8 h;
    h[0] = (_Float16)(a0.x + b0.x); h[1] = (_Float16)(a0.y + b0.y);
    h[2] = (_Float16)(a0.z + b0.z); h[3] = (_Float16)(a0.w + b0.w);
    h[4] = (_Float16)(a1.x + b1.x); h[5] = (_Float16)(a1.y + b1.y);
    h[6] = (_Float16)(a1.z + b1.z); h[7] = (_Float16)(a1.w + b1.w);
    *(half8*)&As[r][c16 * 8] = h;
  }
  __syncthreads();

  f32x4 acc[2][4] = {};
  for (int ks = 0; ks < 16; ++ks) {
    half8 a0 = *(const half8*)&As[lr][ks * 32 + lkb * 8];
    half8 a1 = *(const half8*)&As[16 + lr][ks * 32 + lkb * 8];
    #pragma unroll
    for (int nt = 0; nt < 4; ++nt) {
      half8 bfr = *(const half8*)(WfT + (size_t)(w * 64 + nt * 16 + lr) * 512 +
                                  ks * 32 + lkb * 8);
      acc[0][nt] = mfma16(a0, bfr, acc[0][nt]);
      acc[1][nt] = mfma16(a1, bfr, acc[1][nt]);
    }
  }

  #pragma unroll
  for (int mt = 0; mt < 2; ++mt) {
    #pragma unroll
    for (int nt = 0; nt < 4; ++nt) {
      const int col = w * 64 + nt * 16 + lr;
      const float bias = bf[col];
      #pragma unroll
      for (int i = 0; i < 4; ++i) {
        float v = acc[mt][nt][i] + bias;
        v = 0.5f * v * (1.0f + erff(v * 0.70710678118f));
        Hh[(size_t)(M0 + mt * 16 + lkb * 4 + i) * 512 + col] = (_Float16)v;
      }
    }
  }
}

// ---------------------------------------------------------------------------
// mlp2: out = GroupNorm(Hh @ Wp + bp) -- GN fused in epilogue (each block owns
// complete rows; group = 32 channels = 2 n-tiles within one wave; reduce over
// the 16 lr lanes with shfl_xor).
// ---------------------------------------------------------------------------
__global__ __launch_bounds__(512, 2) void mlp2(
    const _Float16* __restrict__ Hh, const _Float16* __restrict__ WpT,
    const float* __restrict__ bp, const float* __restrict__ gamma,
    const float* __restrict__ beta, float* __restrict__ out)
{
  __shared__ _Float16 As[32][520];
  const int M0 = blockIdx.x * 32;
  const int tid = threadIdx.x;
  const int lane = tid & 63;
  const int w = tid >> 6;
  const int lr = lane & 15;
  const int lkb = lane >> 4;

  #pragma unroll
  for (int j = 0; j < 4; ++j) {
    int c = tid + 512 * j;
    int r = c >> 6, c16 = c & 63;
    half8 h = *(const half8*)(Hh + (size_t)(M0 + r) * 512 + c16 * 8);
    *(half8*)&As[r][c16 * 8] = h;
  }
  __syncthreads();

  f32x4 acc[2][4] = {};
  for (int ks = 0; ks < 16; ++ks) {
    half8 a0 = *(const half8*)&As[lr][ks * 32 + lkb * 8];
    half8 a1 = *(const half8*)&As[16 + lr][ks * 32 + lkb * 8];
    #pragma unroll
    for (int nt = 0; nt < 4; ++nt) {
      half8 b = *(const half8*)(WpT + (size_t)(w * 64 + nt * 16 + lr) * 512 +
                                ks * 32 + lkb * 8);
      acc[0][nt] = mfma16(a0, b, acc[0][nt]);
      acc[1][nt] = mfma16(a1, b, acc[1][nt]);
    }
  }

  #pragma unroll
  for (int mt = 0; mt < 2; ++mt) {
    float vv[4][4];
    #pragma unroll
    for (int nt = 0; nt < 4; ++nt) {
      const float bias = bp[w * 64 + nt * 16 + lr];
      #pragma unroll
      for (int i = 0; i < 4; ++i) vv[nt][i] = acc[mt][nt][i] + bias;
    }
    #pragma unroll
    for (int i = 0; i < 4; ++i) {
      float s0 = vv[0][i] + vv[1][i];
      float q0 = vv[0][i] * vv[0][i] + vv[1][i] * vv[1][i];
      float s1 = vv[2][i] + vv[3][i];
      float q1 = vv[2][i] * vv[2][i] + vv[3][i] * vv[3][i];
      #pragma unroll
      for (int m = 1; m <= 8; m <<= 1) {
        s0 += __shfl_xor(s0, m); q0 += __shfl_xor(q0, m);
        s1 += __shfl_xor(s1, m); q1 += __shfl_xor(q1, m);
      }
      const float mu0 = s0 * (1.0f / 32.0f);
      const float rs0 = rsqrtf(q0 * (1.0f / 32.0f) - mu0 * mu0 + 1e-5f);
      const float mu1 = s1 * (1.0f / 32.0f);
      const float rs1 = rsqrtf(q1 * (1.0f / 32.0f) - mu1 * mu1 + 1e-5f);
      const int row = M0 + mt * 16 + lkb * 4 + i;
      #pragma unroll
      for (int nt = 0; nt < 4; ++nt) {
        const int col = w * 64 + nt * 16 + lr;
        const float mu = (nt < 2) ? mu0 : mu1;
        const float rs = (nt < 2) ? rs0 : rs1;
        out[(size_t)row * 512 + col] =
            (vv[nt][i] - mu) * rs * gamma[col] + beta[col];
      }
    }
  }
}

// ---------------------------------------------------------------------------
extern "C" void kernel_launch(void* const* d_in, const int* in_sizes, int n_in,
                              void* d_out, int out_size, void* d_ws, size_t ws_size,
                              hipStream_t stream)
{
  const float* x  = (const float*)d_in[0];
  const float* D  = (const float*)d_in[1];
  const float* Wq = (const float*)d_in[2];
  const float* bq = (const float*)d_in[3];
  const float* Wk = (const float*)d_in[4];
  const float* bk = (const float*)d_in[5];
  const float* Wv = (const float*)d_in[6];
  const float* bv = (const float*)d_in[7];
  const float* Wf = (const float*)d_in[8];
  const float* bf = (const float*)d_in[9];
  const float* Wp = (const float*)d_in[10];
  const float* bp = (const float*)d_in[11];
  const float* gamma = (const float*)d_in[12];
  const float* beta  = (const float*)d_in[13];

  char* ws = (char*)d_ws;
  const size_t MB = 1024 * 1024;
  _Float16* xh  = (_Float16*)(ws);               //  8 MB (reused as Hh later)
  _Float16* WT  = (_Float16*)(ws + 8 * MB);      //  2.62 MB: 5 transposed f16 W
  _Float16* Qh  = (_Float16*)(ws + 11 * MB);     //  8 MB
  _Float16* Kh  = (_Float16*)(ws + 19 * MB);     //  8 MB
  _Float16* Vt  = (_Float16*)(ws + 27 * MB);     //  8 MB (V transposed [n][m])
  float*    Xp0 = (float*)   (ws + 35 * MB);     // 16 MB
  float*    Xp1 = (float*)   (ws + 51 * MB);     // 16 MB
  _Float16* Hh  = (_Float16*)(ws);               //  8 MB (xh dead after qkv)

  hipLaunchKernelGGL(prep, dim3(896), dim3(256), 0, stream,
                     x, Wq, Wk, Wv, Wf, Wp, xh, WT);
  hipLaunchKernelGGL(qkv, dim3(256), dim3(512), 0, stream,
                     xh, WT, bq, bk, bv, Qh, Kh, Vt);
  hipLaunchKernelGGL(retention, dim3(256), dim3(512), 0, stream,
                     Qh, Kh, Vt, D, Xp0, Xp1);
  hipLaunchKernelGGL(mlp1, dim3(256), dim3(512), 0, stream,
                     Xp0, Xp1, WT + 3 * 262144, bf, Hh);
  hipLaunchKernelGGL(mlp2, dim3(256), dim3(512), 0, stream,
                     Hh, WT + 4 * 262144, bp, gamma, beta, (float*)d_out);
}